// Round 1
// baseline (807.679 us; speedup 1.0000x reference)
//
#include <hip/hip_runtime.h>

// HeteroRGCN forward, MI355X. Key algebraic reductions:
//  - Only h2["target"] feeds the output => layer1 needs only etypes 1,3; layer2 only 0,2.
//    x_card / x_ip are dead inputs.
//  - Layer1 aggregate-first: mean_agg(x@W+b) == (mean_agg(x))@W + b*[deg>0].
//  - Layer2 transform-first, final aggregation fused with 128->2 GEMM + softmax.
// CSR per relation built in d_ws every launch (no float atomics).
// Workspace: ~115 MB.

#define NT 200000
#define NCARD 100000
#define NIP 100000
#define NE 300000

// ---------------- CSR build ----------------

__global__ void hist_k(const int* __restrict__ dst, int* __restrict__ deg, int E) {
  int e = blockIdx.x * blockDim.x + threadIdx.x;
  if (e < E) atomicAdd(&deg[dst[e]], 1);
}

__global__ void scan1_k(const int* __restrict__ deg, int* __restrict__ off,
                        int* __restrict__ bsum, int N) {
  __shared__ int s[256];
  int tid = threadIdx.x;
  int i = blockIdx.x * 256 + tid;
  int v = (i < N) ? deg[i] : 0;
  s[tid] = v;
  __syncthreads();
  for (int o = 1; o < 256; o <<= 1) {
    int t = (tid >= o) ? s[tid - o] : 0;
    __syncthreads();
    s[tid] += t;
    __syncthreads();
  }
  if (i < N) off[i] = s[tid] - v;  // block-local exclusive
  if (tid == 255) bsum[blockIdx.x] = s[255];
}

__global__ void scan2_k(int* bsum, int nb) {
  __shared__ int s[1024];
  int t = threadIdx.x;
  int v = (t < nb) ? bsum[t] : 0;
  s[t] = v;
  __syncthreads();
  for (int o = 1; o < 1024; o <<= 1) {
    int u = (t >= o) ? s[t - o] : 0;
    __syncthreads();
    s[t] += u;
    __syncthreads();
  }
  if (t < nb) bsum[t] = s[t] - v;  // exclusive across blocks
}

__global__ void scan3_k(int* __restrict__ off, const int* __restrict__ bsum,
                        int* __restrict__ cur, int N) {
  int i = blockIdx.x * 256 + threadIdx.x;
  if (i < N) {
    int v = off[i] + bsum[blockIdx.x];
    off[i] = v;
    cur[i] = v;
  }
}

__global__ void fill_k(const int* __restrict__ src, const int* __restrict__ dst,
                       int* __restrict__ cur, int* __restrict__ csr, int E) {
  int e = blockIdx.x * blockDim.x + threadIdx.x;
  if (e < E) {
    int slot = atomicAdd(&cur[dst[e]], 1);
    csr[slot] = src[e];
  }
}

// ---------------- aggregation (one wave per dst row, sum only) ----------------

__global__ void agg_k(const float* __restrict__ x, const int* __restrict__ off,
                      const int* __restrict__ deg, const int* __restrict__ csr,
                      float* __restrict__ acc, int nrows) {
  int gt = blockIdx.x * blockDim.x + threadIdx.x;
  int row = gt >> 6, lane = gt & 63;
  if (row >= nrows) return;
  int start = off[row], cnt = deg[row];
  float ax = 0.f, ay = 0.f;
  for (int i = 0; i < cnt; i++) {
    int s = csr[start + i];
    float2 v = ((const float2*)(x + (size_t)s * 128))[lane];
    ax += v.x;
    ay += v.y;
  }
  ((float2*)(acc + (size_t)row * 128))[lane] = make_float2(ax, ay);
}

// ---------------- row-wise GEMM: out[r] = f((in[r]/deg)@W + b) ----------------
// In-place safe: a block only reads/writes its own 64 rows; all loads precede stores.
// NOTE: in/out intentionally NOT __restrict__ (aliased for in-place use).

__global__ __launch_bounds__(256) void gemm_k(const float* in, float* out,
                                              const float* __restrict__ W,
                                              const float* __restrict__ bias,
                                              const int* __restrict__ deg, int M,
                                              int leaky) {
  __shared__ float sIn[64][36];   // padded: row stride 144B (16B aligned)
  __shared__ float sW[32][132];   // padded: row stride 528B (16B aligned)
  int tid = threadIdx.x;
  int tx = tid & 31, ty = tid >> 5;  // tx: col group (4 cols), ty: row group (8 rows)
  int r0 = blockIdx.x * 64;
  float acc[8][4];
#pragma unroll
  for (int i = 0; i < 8; i++) {
    acc[i][0] = 0.f; acc[i][1] = 0.f; acc[i][2] = 0.f; acc[i][3] = 0.f;
  }
  for (int kc = 0; kc < 128; kc += 32) {
    // stage W[kc..kc+32) x 128  (4096 floats, 4 float4/thread)
#pragma unroll
    for (int q = 0; q < 4; q++) {
      int f = tid + q * 256;
      int kr = f >> 5, c4 = f & 31;
      float4 w = ((const float4*)(W + (size_t)(kc + kr) * 128))[c4];
      *(float4*)&sW[kr][c4 * 4] = w;
    }
    // stage in rows r0..r0+64 x 32 k's (2048 floats, 2 float4/thread)
#pragma unroll
    for (int q = 0; q < 2; q++) {
      int f = tid + q * 256;
      int rr = f >> 3, c4 = f & 7;
      int gr = r0 + rr;
      float4 v = make_float4(0.f, 0.f, 0.f, 0.f);
      if (gr < M) v = ((const float4*)(in + (size_t)gr * 128 + kc))[c4];
      *(float4*)&sIn[rr][c4 * 4] = v;
    }
    __syncthreads();
#pragma unroll
    for (int k = 0; k < 32; k++) {
      float4 w4 = *(const float4*)&sW[k][tx * 4];
#pragma unroll
      for (int ii = 0; ii < 8; ii++) {
        float a = sIn[ty * 8 + ii][k];
        acc[ii][0] += a * w4.x;
        acc[ii][1] += a * w4.y;
        acc[ii][2] += a * w4.z;
        acc[ii][3] += a * w4.w;
      }
    }
    __syncthreads();
  }
  float4 b4 = ((const float4*)bias)[tx];
#pragma unroll
  for (int ii = 0; ii < 8; ii++) {
    int r = r0 + ty * 8 + ii;
    if (r >= M) continue;
    float sc = 1.f;
    bool zr = false;
    if (deg) {
      int d = deg[r];
      if (d > 0) sc = 1.f / (float)d; else zr = true;
    }
    float4 v;
    v.x = zr ? 0.f : (acc[ii][0] * sc + b4.x);
    v.y = zr ? 0.f : (acc[ii][1] * sc + b4.y);
    v.z = zr ? 0.f : (acc[ii][2] * sc + b4.z);
    v.w = zr ? 0.f : (acc[ii][3] * sc + b4.w);
    if (leaky) {
      v.x = v.x > 0.f ? v.x : 0.01f * v.x;
      v.y = v.y > 0.f ? v.y : 0.01f * v.y;
      v.z = v.z > 0.f ? v.z : 0.01f * v.z;
      v.w = v.w > 0.f ? v.w : 0.01f * v.w;
    }
    ((float4*)(out + (size_t)r * 128))[tx] = v;
  }
}

// ------- final: target agg over e0,e2 + 128->2 GEMM + softmax, one wave/row -------

__global__ void final_k(const float* __restrict__ tc, const float* __restrict__ ti,
                        const int* __restrict__ off0, const int* __restrict__ deg0,
                        const int* __restrict__ csr0, const int* __restrict__ off2,
                        const int* __restrict__ deg2, const int* __restrict__ csr2,
                        const float* __restrict__ wout, const float* __restrict__ bout,
                        float* __restrict__ out) {
  int gt = blockIdx.x * blockDim.x + threadIdx.x;
  int row = gt >> 6, lane = gt & 63;
  if (row >= NT) return;
  float hx = 0.f, hy = 0.f;
  {
    int st = off0[row], d = deg0[row];
    float ax = 0.f, ay = 0.f;
    for (int i = 0; i < d; i++) {
      int s = csr0[st + i];
      float2 v = ((const float2*)(tc + (size_t)s * 128))[lane];
      ax += v.x; ay += v.y;
    }
    if (d > 0) { float inv = 1.f / (float)d; hx += ax * inv; hy += ay * inv; }
  }
  {
    int st = off2[row], d = deg2[row];
    float ax = 0.f, ay = 0.f;
    for (int i = 0; i < d; i++) {
      int s = csr2[st + i];
      float2 v = ((const float2*)(ti + (size_t)s * 128))[lane];
      ax += v.x; ay += v.y;
    }
    if (d > 0) { float inv = 1.f / (float)d; hx += ax * inv; hy += ay * inv; }
  }
  // logits: lane holds h[2*lane], h[2*lane+1]; wout is [128][2] row-major
  float4 w4 = ((const float4*)wout)[lane];
  float l0 = hx * w4.x + hy * w4.z;
  float l1 = hx * w4.y + hy * w4.w;
#pragma unroll
  for (int o = 32; o; o >>= 1) {
    l0 += __shfl_xor(l0, o);
    l1 += __shfl_xor(l1, o);
  }
  if (lane == 0) {
    l0 += bout[0];
    l1 += bout[1];
    float m = fmaxf(l0, l1);
    float e0 = expf(l0 - m), e1 = expf(l1 - m);
    float inv = 1.f / (e0 + e1);
    ((float2*)out)[row] = make_float2(e0 * inv, e1 * inv);
  }
}

// ---------------- launch ----------------

extern "C" void kernel_launch(void* const* d_in, const int* in_sizes, int n_in,
                              void* d_out, int out_size, void* d_ws, size_t ws_size,
                              hipStream_t stream) {
  const float* x_target = (const float*)d_in[0];
  // d_in[1] = x_card (dead), d_in[2] = x_ip (dead)
  const float* w1 = (const float*)d_in[3];
  const float* b1 = (const float*)d_in[4];
  const float* w2 = (const float*)d_in[5];
  const float* b2 = (const float*)d_in[6];
  const float* wout = (const float*)d_in[7];
  const float* bout = (const float*)d_in[8];
  const int* src0 = (const int*)d_in[9];
  const int* dst0 = (const int*)d_in[10];
  const int* src1 = (const int*)d_in[11];
  const int* dst1 = (const int*)d_in[12];
  const int* src2 = (const int*)d_in[13];
  const int* dst2 = (const int*)d_in[14];
  const int* src3 = (const int*)d_in[15];
  const int* dst3 = (const int*)d_in[16];
  float* out = (float*)d_out;

  char* p = (char*)d_ws;
  auto ialloc = [&](size_t n) -> int* {
    int* r = (int*)p;
    p += n * sizeof(int);
    return r;
  };
  int* deg1 = ialloc(NCARD); int* cur1 = ialloc(NCARD);
  int* deg3 = ialloc(NIP);   int* cur3 = ialloc(NIP);
  int* deg0 = ialloc(NT);    int* cur0 = ialloc(NT);
  int* deg2 = ialloc(NT);    int* cur2 = ialloc(NT);
  size_t zero_bytes = (size_t)(p - (char*)d_ws);  // deg+cur arrays must start at 0
  int* off1 = ialloc(NCARD);
  int* off3 = ialloc(NIP);
  int* off0 = ialloc(NT);
  int* off2 = ialloc(NT);
  int* bs1 = ialloc(1024); int* bs3 = ialloc(1024);
  int* bs0 = ialloc(1024); int* bs2 = ialloc(1024);
  int* csr1 = ialloc(NE); int* csr3 = ialloc(NE);
  int* csr0 = ialloc(NE); int* csr2 = ialloc(NE);
  float* accC = (float*)p; p += (size_t)NCARD * 128 * sizeof(float);
  float* accI = (float*)p; p += (size_t)NIP * 128 * sizeof(float);

  hipMemsetAsync(d_ws, 0, zero_bytes, stream);

  int eb = (NE + 255) / 256;
  hist_k<<<eb, 256, 0, stream>>>(dst1, deg1, NE);
  hist_k<<<eb, 256, 0, stream>>>(dst3, deg3, NE);
  hist_k<<<eb, 256, 0, stream>>>(dst0, deg0, NE);
  hist_k<<<eb, 256, 0, stream>>>(dst2, deg2, NE);

  auto build = [&](const int* src, const int* dst, int* deg, int* off, int* bs,
                   int* cur, int* csr, int N) {
    int nb = (N + 255) / 256;
    scan1_k<<<nb, 256, 0, stream>>>(deg, off, bs, N);
    scan2_k<<<1, 1024, 0, stream>>>(bs, nb);
    scan3_k<<<nb, 256, 0, stream>>>(off, bs, cur, N);
    fill_k<<<eb, 256, 0, stream>>>(src, dst, cur, csr, NE);
  };
  build(src1, dst1, deg1, off1, bs1, cur1, csr1, NCARD);
  build(src3, dst3, deg3, off3, bs3, cur3, csr3, NIP);
  build(src0, dst0, deg0, off0, bs0, cur0, csr0, NT);
  build(src2, dst2, deg2, off2, bs2, cur2, csr2, NT);

  // layer1 aggregate-first (sums; GEMM divides by deg)
  agg_k<<<NCARD / 4, 256, 0, stream>>>(x_target, off1, deg1, csr1, accC, NCARD);
  agg_k<<<NIP / 4, 256, 0, stream>>>(x_target, off3, deg3, csr3, accI, NIP);

  int gbC = (NCARD + 63) / 64, gbI = (NIP + 63) / 64;
  // layer1 transform: h1 = leaky((acc/deg)@W1[et] + b1[et]) with deg==0 -> 0
  gemm_k<<<gbC, 256, 0, stream>>>(accC, accC, w1 + 1 * 16384, b1 + 128, deg1, NCARD, 1);
  gemm_k<<<gbI, 256, 0, stream>>>(accI, accI, w1 + 3 * 16384, b1 + 384, deg3, NIP, 1);
  // layer2 transform-first: t = h1@W2[et] + b2[et]
  gemm_k<<<gbC, 256, 0, stream>>>(accC, accC, w2 + 0 * 16384, b2 + 0, nullptr, NCARD, 0);
  gemm_k<<<gbI, 256, 0, stream>>>(accI, accI, w2 + 2 * 16384, b2 + 256, nullptr, NIP, 0);

  // fused target aggregation + output GEMM + softmax
  final_k<<<NT / 4, 256, 0, stream>>>(accC, accI, off0, deg0, csr0, off2, deg2, csr2,
                                      wout, bout, out);
}

// Round 2
// 530.007 us; speedup vs baseline: 1.5239x; 1.5239x over previous
//
#include <hip/hip_runtime.h>

// HeteroRGCN forward, MI355X. Algebraic structure:
//  - Only h2["target"] feeds the output => layer1 needs only etypes 1,3; layer2 only 0,2.
//  - Layer1 aggregate-first: mean_agg(x@W+b) == (mean_agg(x))@W + b*[deg>0].
//  - Layer2 + output GEMM folded: z = leaky(h1) @ (W2@wout) + b2@wout  (2 floats/node),
//    computed in the layer1 GEMM epilogue; h1 never hits memory.
//  - Target-side aggregation: edge-parallel 8B scatter of z with float atomics
//    (no CSR needed for e0/e2), then per-row mean + softmax.
// CSR (e1,e3 only) built in d_ws every launch. Workspace ~114 MB.

#define NT 200000
#define NCARD 100000
#define NIP 100000
#define NE 300000

// ---------------- degree histograms, all 4 relations in one launch ----------------

__global__ void hist4_k(const int* __restrict__ d1, const int* __restrict__ d3,
                        const int* __restrict__ d0, const int* __restrict__ d2,
                        int* __restrict__ g1, int* __restrict__ g3,
                        int* __restrict__ g0, int* __restrict__ g2) {
  int t = blockIdx.x * 256 + threadIdx.x;
  if (t < NE) atomicAdd(&g1[d1[t]], 1);
  else if (t < 2 * NE) atomicAdd(&g3[d3[t - NE]], 1);
  else if (t < 3 * NE) atomicAdd(&g0[d0[t - 2 * NE]], 1);
  else if (t < 4 * NE) atomicAdd(&g2[d2[t - 3 * NE]], 1);
}

// ---------------- CSR build (e1 -> card, e3 -> ip), fused scans ----------------

__global__ void scan1f_k(const int* __restrict__ deg1, int* __restrict__ off1,
                         int* __restrict__ bs1, int nb1, int N1,
                         const int* __restrict__ deg3, int* __restrict__ off3,
                         int* __restrict__ bs3, int N3) {
  __shared__ int s[256];
  int bid = blockIdx.x;
  const int* deg; int* off; int* bsum; int N; int lb;
  if (bid < nb1) { deg = deg1; off = off1; bsum = bs1; N = N1; lb = bid; }
  else { deg = deg3; off = off3; bsum = bs3; N = N3; lb = bid - nb1; }
  int tid = threadIdx.x;
  int i = lb * 256 + tid;
  int v = (i < N) ? deg[i] : 0;
  s[tid] = v;
  __syncthreads();
  for (int o = 1; o < 256; o <<= 1) {
    int t = (tid >= o) ? s[tid - o] : 0;
    __syncthreads();
    s[tid] += t;
    __syncthreads();
  }
  if (i < N) off[i] = s[tid] - v;
  if (tid == 255) bsum[lb] = s[255];
}

__global__ void scan2f_k(int* __restrict__ bs1, int nb1, int* __restrict__ bs3, int nb3) {
  __shared__ int s[1024];
  int* bs = blockIdx.x == 0 ? bs1 : bs3;
  int nb = blockIdx.x == 0 ? nb1 : nb3;
  int t = threadIdx.x;
  int v = (t < nb) ? bs[t] : 0;
  s[t] = v;
  __syncthreads();
  for (int o = 1; o < 1024; o <<= 1) {
    int u = (t >= o) ? s[t - o] : 0;
    __syncthreads();
    s[t] += u;
    __syncthreads();
  }
  if (t < nb) bs[t] = s[t] - v;
}

__global__ void scan3f_k(int* __restrict__ off1, const int* __restrict__ bs1,
                         int* __restrict__ cur1, int nb1, int N1,
                         int* __restrict__ off3, const int* __restrict__ bs3,
                         int* __restrict__ cur3, int N3) {
  int bid = blockIdx.x;
  int* off; const int* bsum; int* cur; int N; int lb;
  if (bid < nb1) { off = off1; bsum = bs1; cur = cur1; N = N1; lb = bid; }
  else { off = off3; bsum = bs3; cur = cur3; N = N3; lb = bid - nb1; }
  int i = lb * 256 + threadIdx.x;
  if (i < N) {
    int v = off[i] + bsum[lb];
    off[i] = v;
    cur[i] = v;
  }
}

__global__ void fillf_k(const int* __restrict__ s1, const int* __restrict__ d1,
                        int* __restrict__ cur1, int* __restrict__ csr1,
                        const int* __restrict__ s3, const int* __restrict__ d3,
                        int* __restrict__ cur3, int* __restrict__ csr3) {
  int t = blockIdx.x * 256 + threadIdx.x;
  if (t < NE) {
    int slot = atomicAdd(&cur1[d1[t]], 1);
    csr1[slot] = s1[t];
  } else if (t < 2 * NE) {
    int e = t - NE;
    int slot = atomicAdd(&cur3[d3[e]], 1);
    csr3[slot] = s3[e];
  }
}

// ------- layer1 source aggregation: sum of x_target rows per card/ip node -------
// 32 lanes per row (float4), 2 rows per wave, 2-edge unroll for load ILP.

__global__ void aggf_k(const float* __restrict__ x,
                       const int* __restrict__ off1, const int* __restrict__ deg1,
                       const int* __restrict__ csr1, float* __restrict__ accC,
                       const int* __restrict__ off3, const int* __restrict__ deg3,
                       const int* __restrict__ csr3, float* __restrict__ accI) {
  int gt = blockIdx.x * 256 + threadIdx.x;
  int rid = gt >> 5, lane = gt & 31;
  if (rid >= NCARD + NIP) return;
  const int* off; const int* deg; const int* csr; float* acc; int row;
  if (rid < NCARD) { off = off1; deg = deg1; csr = csr1; acc = accC; row = rid; }
  else { off = off3; deg = deg3; csr = csr3; acc = accI; row = rid - NCARD; }
  int start = off[row], cnt = deg[row];
  float4 a0 = make_float4(0.f, 0.f, 0.f, 0.f);
  float4 a1 = make_float4(0.f, 0.f, 0.f, 0.f);
  int i = 0;
  for (; i + 2 <= cnt; i += 2) {
    int s0 = csr[start + i], s1 = csr[start + i + 1];
    float4 v0 = ((const float4*)(x + (size_t)s0 * 128))[lane];
    float4 v1 = ((const float4*)(x + (size_t)s1 * 128))[lane];
    a0.x += v0.x; a0.y += v0.y; a0.z += v0.z; a0.w += v0.w;
    a1.x += v1.x; a1.y += v1.y; a1.z += v1.z; a1.w += v1.w;
  }
  if (i < cnt) {
    int s0 = csr[start + i];
    float4 v0 = ((const float4*)(x + (size_t)s0 * 128))[lane];
    a0.x += v0.x; a0.y += v0.y; a0.z += v0.z; a0.w += v0.w;
  }
  a0.x += a1.x; a0.y += a1.y; a0.z += a1.z; a0.w += a1.w;
  ((float4*)(acc + (size_t)row * 128))[lane] = a0;
}

// ------- fold W2@wout and b2@wout (once per launch, trivial) -------

__global__ void prep_k(const float* __restrict__ w2, const float* __restrict__ b2,
                       const float* __restrict__ wout, float* __restrict__ wfC,
                       float* __restrict__ wfI, float* __restrict__ bfC,
                       float* __restrict__ bfI) {
  int t = threadIdx.x;  // 256 threads: k = t>>1, o = t&1
  int k = t >> 1, o = t & 1;
  float sC = 0.f, sI = 0.f;
  for (int j = 0; j < 128; j++) {
    float wo = wout[j * 2 + o];
    sC += w2[0 * 16384 + k * 128 + j] * wo;
    sI += w2[2 * 16384 + k * 128 + j] * wo;
  }
  wfC[k * 2 + o] = sC;
  wfI[k * 2 + o] = sI;
  if (t < 2) {
    float s = 0.f;
    for (int j = 0; j < 128; j++) s += b2[0 * 128 + j] * wout[j * 2 + t];
    bfC[t] = s;
  } else if (t < 4) {
    int oo = t - 2;
    float s = 0.f;
    for (int j = 0; j < 128; j++) s += b2[2 * 128 + j] * wout[j * 2 + oo];
    bfI[oo] = s;
  }
}

// ------- layer1 GEMM + leaky + fold-to-z epilogue (both regions, one launch) -------
// z[r] = leaky((acc[r]/deg)@W1 + b1 ; 0 if deg==0) @ Wfold + bfold   (2 floats/row)

__global__ __launch_bounds__(256) void gemm_zf_k(
    const float* __restrict__ accC, const float* __restrict__ accI,
    const float* __restrict__ w1, const float* __restrict__ b1,
    const int* __restrict__ deg1, const int* __restrict__ deg3,
    const float* __restrict__ wfC, const float* __restrict__ wfI,
    const float* __restrict__ bfC, const float* __restrict__ bfI,
    float* __restrict__ zc, float* __restrict__ zi, int gbC) {
  __shared__ float sIn[64][36];
  __shared__ float sW[32][132];
  int bid = blockIdx.x;
  const float* in; const float* W; const float* bias; const int* deg;
  const float* wf; const float* bf; float* zout; int M; int lb;
  if (bid < gbC) {
    in = accC; W = w1 + 1 * 16384; bias = b1 + 128; deg = deg1;
    wf = wfC; bf = bfC; zout = zc; M = NCARD; lb = bid;
  } else {
    in = accI; W = w1 + 3 * 16384; bias = b1 + 384; deg = deg3;
    wf = wfI; bf = bfI; zout = zi; M = NIP; lb = bid - gbC;
  }
  int tid = threadIdx.x;
  int tx = tid & 31, ty = tid >> 5;
  int r0 = lb * 64;
  float acc[8][4];
#pragma unroll
  for (int i = 0; i < 8; i++) {
    acc[i][0] = 0.f; acc[i][1] = 0.f; acc[i][2] = 0.f; acc[i][3] = 0.f;
  }
  for (int kc = 0; kc < 128; kc += 32) {
#pragma unroll
    for (int q = 0; q < 4; q++) {
      int f = tid + q * 256;
      int kr = f >> 5, c4 = f & 31;
      float4 w = ((const float4*)(W + (size_t)(kc + kr) * 128))[c4];
      *(float4*)&sW[kr][c4 * 4] = w;
    }
#pragma unroll
    for (int q = 0; q < 2; q++) {
      int f = tid + q * 256;
      int rr = f >> 3, c4 = f & 7;
      int gr = r0 + rr;
      float4 v = make_float4(0.f, 0.f, 0.f, 0.f);
      if (gr < M) v = ((const float4*)(in + (size_t)gr * 128 + kc))[c4];
      *(float4*)&sIn[rr][c4 * 4] = v;
    }
    __syncthreads();
#pragma unroll
    for (int k = 0; k < 32; k++) {
      float4 w4 = *(const float4*)&sW[k][tx * 4];
#pragma unroll
      for (int ii = 0; ii < 8; ii++) {
        float a = sIn[ty * 8 + ii][k];
        acc[ii][0] += a * w4.x;
        acc[ii][1] += a * w4.y;
        acc[ii][2] += a * w4.z;
        acc[ii][3] += a * w4.w;
      }
    }
    __syncthreads();
  }
  float4 b4 = ((const float4*)bias)[tx];
  // Wfold rows 4tx..4tx+3: wf0=(W[4tx][0],W[4tx][1],W[4tx+1][0],W[4tx+1][1]), etc.
  float4 wf0 = ((const float4*)wf)[tx * 2];
  float4 wf1 = ((const float4*)wf)[tx * 2 + 1];
  float2 bf2 = *(const float2*)bf;
#pragma unroll
  for (int ii = 0; ii < 8; ii++) {
    int r = r0 + ty * 8 + ii;
    float h0, h1, h2, h3;
    int d = (r < M) ? deg[r] : 0;
    if (d > 0) {
      float sc = 1.f / (float)d;
      h0 = acc[ii][0] * sc + b4.x;
      h1 = acc[ii][1] * sc + b4.y;
      h2 = acc[ii][2] * sc + b4.z;
      h3 = acc[ii][3] * sc + b4.w;
      h0 = h0 > 0.f ? h0 : 0.01f * h0;
      h1 = h1 > 0.f ? h1 : 0.01f * h1;
      h2 = h2 > 0.f ? h2 : 0.01f * h2;
      h3 = h3 > 0.f ? h3 : 0.01f * h3;
    } else {
      h0 = h1 = h2 = h3 = 0.f;
    }
    float pz0 = h0 * wf0.x + h1 * wf0.z + h2 * wf1.x + h3 * wf1.z;
    float pz1 = h0 * wf0.y + h1 * wf0.w + h2 * wf1.y + h3 * wf1.w;
#pragma unroll
    for (int o = 1; o < 32; o <<= 1) {
      pz0 += __shfl_xor(pz0, o);
      pz1 += __shfl_xor(pz1, o);
    }
    if (tx == 0 && r < M) {
      ((float2*)zout)[r] = make_float2(pz0 + bf2.x, pz1 + bf2.y);
    }
  }
}

// ------- target-side: edge-parallel scatter of z (8B per edge), both relations -------

__global__ void scatterf_k(const int* __restrict__ s0, const int* __restrict__ d0,
                           const float* __restrict__ zc, float* __restrict__ tsum0,
                           const int* __restrict__ s2, const int* __restrict__ d2,
                           const float* __restrict__ zi, float* __restrict__ tsum2) {
  int t = blockIdx.x * 256 + threadIdx.x;
  if (t < NE) {
    float2 z = ((const float2*)zc)[s0[t]];
    int d = d0[t];
    atomicAdd(&tsum0[d * 2], z.x);
    atomicAdd(&tsum0[d * 2 + 1], z.y);
  } else if (t < 2 * NE) {
    int e = t - NE;
    float2 z = ((const float2*)zi)[s2[e]];
    int d = d2[e];
    atomicAdd(&tsum2[d * 2], z.x);
    atomicAdd(&tsum2[d * 2 + 1], z.y);
  }
}

// ------- per-target mean over both relations + bout + softmax -------

__global__ void final3_k(const float* __restrict__ tsum0, const int* __restrict__ deg0,
                         const float* __restrict__ tsum2, const int* __restrict__ deg2,
                         const float* __restrict__ bout, float* __restrict__ out) {
  int t = blockIdx.x * 256 + threadIdx.x;
  if (t >= NT) return;
  float l0 = bout[0], l1 = bout[1];
  int d0 = deg0[t];
  if (d0 > 0) {
    float inv = 1.f / (float)d0;
    l0 += tsum0[t * 2] * inv;
    l1 += tsum0[t * 2 + 1] * inv;
  }
  int d2 = deg2[t];
  if (d2 > 0) {
    float inv = 1.f / (float)d2;
    l0 += tsum2[t * 2] * inv;
    l1 += tsum2[t * 2 + 1] * inv;
  }
  float m = fmaxf(l0, l1);
  float e0 = expf(l0 - m), e1 = expf(l1 - m);
  float inv = 1.f / (e0 + e1);
  ((float2*)out)[t] = make_float2(e0 * inv, e1 * inv);
}

// ---------------- launch ----------------

extern "C" void kernel_launch(void* const* d_in, const int* in_sizes, int n_in,
                              void* d_out, int out_size, void* d_ws, size_t ws_size,
                              hipStream_t stream) {
  const float* x_target = (const float*)d_in[0];
  const float* w1 = (const float*)d_in[3];
  const float* b1 = (const float*)d_in[4];
  const float* w2 = (const float*)d_in[5];
  const float* b2 = (const float*)d_in[6];
  const float* wout = (const float*)d_in[7];
  const float* bout = (const float*)d_in[8];
  const int* src0 = (const int*)d_in[9];
  const int* dst0 = (const int*)d_in[10];
  const int* src1 = (const int*)d_in[11];
  const int* dst1 = (const int*)d_in[12];
  const int* src2 = (const int*)d_in[13];
  const int* dst2 = (const int*)d_in[14];
  const int* src3 = (const int*)d_in[15];
  const int* dst3 = (const int*)d_in[16];
  float* out = (float*)d_out;

  char* p = (char*)d_ws;
  auto alloc = [&](size_t bytes) -> char* {
    char* r = p;
    p += (bytes + 255) & ~(size_t)255;  // 256B align
    return r;
  };
  // --- zero region (memset every launch) ---
  int* deg1 = (int*)alloc(NCARD * 4);
  int* cur1 = (int*)alloc(NCARD * 4);
  int* deg3 = (int*)alloc(NIP * 4);
  int* cur3 = (int*)alloc(NIP * 4);
  int* deg0 = (int*)alloc(NT * 4);
  int* deg2 = (int*)alloc(NT * 4);
  float* tsum0 = (float*)alloc((size_t)NT * 2 * 4);
  float* tsum2 = (float*)alloc((size_t)NT * 2 * 4);
  size_t zero_bytes = (size_t)(p - (char*)d_ws);
  // --- rest ---
  int* off1 = (int*)alloc(NCARD * 4);
  int* off3 = (int*)alloc(NIP * 4);
  int* bs1 = (int*)alloc(1024 * 4);
  int* bs3 = (int*)alloc(1024 * 4);
  int* csr1 = (int*)alloc(NE * 4);
  int* csr3 = (int*)alloc(NE * 4);
  float* accC = (float*)alloc((size_t)NCARD * 128 * 4);
  float* accI = (float*)alloc((size_t)NIP * 128 * 4);
  float* zc = (float*)alloc((size_t)NCARD * 2 * 4);
  float* zi = (float*)alloc((size_t)NIP * 2 * 4);
  float* wfC = (float*)alloc(256 * 4);
  float* wfI = (float*)alloc(256 * 4);
  float* bfC = (float*)alloc(2 * 4);
  float* bfI = (float*)alloc(2 * 4);

  hipMemsetAsync(d_ws, 0, zero_bytes, stream);

  hist4_k<<<(4 * NE + 255) / 256, 256, 0, stream>>>(dst1, dst3, dst0, dst2,
                                                    deg1, deg3, deg0, deg2);
  int nb1 = (NCARD + 255) / 256, nb3 = (NIP + 255) / 256;
  scan1f_k<<<nb1 + nb3, 256, 0, stream>>>(deg1, off1, bs1, nb1, NCARD,
                                          deg3, off3, bs3, NIP);
  scan2f_k<<<2, 1024, 0, stream>>>(bs1, nb1, bs3, nb3);
  scan3f_k<<<nb1 + nb3, 256, 0, stream>>>(off1, bs1, cur1, nb1, NCARD,
                                          off3, bs3, cur3, NIP);
  fillf_k<<<(2 * NE + 255) / 256, 256, 0, stream>>>(src1, dst1, cur1, csr1,
                                                    src3, dst3, cur3, csr3);

  prep_k<<<1, 256, 0, stream>>>(w2, b2, wout, wfC, wfI, bfC, bfI);

  aggf_k<<<((NCARD + NIP) * 32 + 255) / 256, 256, 0, stream>>>(
      x_target, off1, deg1, csr1, accC, off3, deg3, csr3, accI);

  int gbC = (NCARD + 63) / 64, gbI = (NIP + 63) / 64;
  gemm_zf_k<<<gbC + gbI, 256, 0, stream>>>(accC, accI, w1, b1, deg1, deg3,
                                           wfC, wfI, bfC, bfI, zc, zi, gbC);

  scatterf_k<<<(2 * NE + 255) / 256, 256, 0, stream>>>(src0, dst0, zc, tsum0,
                                                       src2, dst2, zi, tsum2);

  final3_k<<<(NT + 255) / 256, 256, 0, stream>>>(tsum0, deg0, tsum2, deg2, bout, out);
}

// Round 3
// 469.240 us; speedup vs baseline: 1.7212x; 1.1295x over previous
//
#include <hip/hip_runtime.h>

// HeteroRGCN forward, MI355X. Structure (see round 1/2 notes):
//  - Only h2["target"] matters => layer1 etypes 1,3; layer2 etypes 0,2. x_card/x_ip dead.
//  - Layer1 aggregate-first; layer2+output folded to Wfold=W2@wout (2 cols).
//  - Round 3: bf16 storage + MFMA 16x16x32 for the 128x128 transform; x_target
//    converted to bf16 once so the irregular gather moves 256B/row not 512B.
//    All accumulation fp32.

#define NT 200000
#define NCARD 100000
#define NIP 100000
#define NE 300000

typedef __attribute__((ext_vector_type(8))) short s8v;   // 8 bf16 (4 VGPRs)
typedef __attribute__((ext_vector_type(4))) float f4v;   // mfma accumulator

__device__ __forceinline__ unsigned short f2b(float f) {
  unsigned u = __float_as_uint(f);
  u = (u + 0x7fff + ((u >> 16) & 1)) >> 16;  // RNE (finite inputs)
  return (unsigned short)u;
}

// ---------------- degree histograms, all 4 relations in one launch ----------------

__global__ void hist4_k(const int* __restrict__ d1, const int* __restrict__ d3,
                        const int* __restrict__ d0, const int* __restrict__ d2,
                        int* __restrict__ g1, int* __restrict__ g3,
                        int* __restrict__ g0, int* __restrict__ g2) {
  int t = blockIdx.x * 256 + threadIdx.x;
  if (t < NE) atomicAdd(&g1[d1[t]], 1);
  else if (t < 2 * NE) atomicAdd(&g3[d3[t - NE]], 1);
  else if (t < 3 * NE) atomicAdd(&g0[d0[t - 2 * NE]], 1);
  else if (t < 4 * NE) atomicAdd(&g2[d2[t - 3 * NE]], 1);
}

// ---------------- CSR build (e1 -> card, e3 -> ip) ----------------

__global__ void scan1f_k(const int* __restrict__ deg1, int* __restrict__ off1,
                         int* __restrict__ bs1, int nb1, int N1,
                         const int* __restrict__ deg3, int* __restrict__ off3,
                         int* __restrict__ bs3, int N3) {
  __shared__ int s[256];
  int bid = blockIdx.x;
  const int* deg; int* off; int* bsum; int N; int lb;
  if (bid < nb1) { deg = deg1; off = off1; bsum = bs1; N = N1; lb = bid; }
  else { deg = deg3; off = off3; bsum = bs3; N = N3; lb = bid - nb1; }
  int tid = threadIdx.x;
  int i = lb * 256 + tid;
  int v = (i < N) ? deg[i] : 0;
  s[tid] = v;
  __syncthreads();
  for (int o = 1; o < 256; o <<= 1) {
    int t = (tid >= o) ? s[tid - o] : 0;
    __syncthreads();
    s[tid] += t;
    __syncthreads();
  }
  if (i < N) off[i] = s[tid] - v;
  if (tid == 255) bsum[lb] = s[255];
}

__global__ void scan2f_k(int* __restrict__ bs1, int nb1, int* __restrict__ bs3, int nb3) {
  __shared__ int s[1024];
  int* bs = blockIdx.x == 0 ? bs1 : bs3;
  int nb = blockIdx.x == 0 ? nb1 : nb3;
  int t = threadIdx.x;
  int v = (t < nb) ? bs[t] : 0;
  s[t] = v;
  __syncthreads();
  for (int o = 1; o < 1024; o <<= 1) {
    int u = (t >= o) ? s[t - o] : 0;
    __syncthreads();
    s[t] += u;
    __syncthreads();
  }
  if (t < nb) bs[t] = s[t] - v;
}

__global__ void scan3f_k(int* __restrict__ off1, const int* __restrict__ bs1,
                         int* __restrict__ cur1, int nb1, int N1,
                         int* __restrict__ off3, const int* __restrict__ bs3,
                         int* __restrict__ cur3, int N3) {
  int bid = blockIdx.x;
  int* off; const int* bsum; int* cur; int N; int lb;
  if (bid < nb1) { off = off1; bsum = bs1; cur = cur1; N = N1; lb = bid; }
  else { off = off3; bsum = bs3; cur = cur3; N = N3; lb = bid - nb1; }
  int i = lb * 256 + threadIdx.x;
  if (i < N) {
    int v = off[i] + bsum[lb];
    off[i] = v;
    cur[i] = v;
  }
}

__global__ void fillf_k(const int* __restrict__ s1, const int* __restrict__ d1,
                        int* __restrict__ cur1, int* __restrict__ csr1,
                        const int* __restrict__ s3, const int* __restrict__ d3,
                        int* __restrict__ cur3, int* __restrict__ csr3) {
  int t = blockIdx.x * 256 + threadIdx.x;
  if (t < NE) {
    int slot = atomicAdd(&cur1[d1[t]], 1);
    csr1[slot] = s1[t];
  } else if (t < 2 * NE) {
    int e = t - NE;
    int slot = atomicAdd(&cur3[d3[e]], 1);
    csr3[slot] = s3[e];
  }
}

// ---------------- fp32 -> bf16 conversion of x_target ----------------

__global__ void cvt_k(const float* __restrict__ x, unsigned short* __restrict__ xb) {
  long i = (long)blockIdx.x * 256 + threadIdx.x;  // one float4 per thread
  const long n4 = (long)NT * 128 / 4;
  if (i >= n4) return;
  float4 v = ((const float4*)x)[i];
  uint2 o;
  o.x = (unsigned)f2b(v.x) | ((unsigned)f2b(v.y) << 16);
  o.y = (unsigned)f2b(v.z) | ((unsigned)f2b(v.w) << 16);
  ((uint2*)xb)[i] = o;
}

// ---- W1[1], W1[3] -> bf16, transposed to [n][k] for MFMA B-fragments ----

__global__ void wt_k(const float* __restrict__ w1, unsigned short* __restrict__ wtC,
                     unsigned short* __restrict__ wtI) {
  int t = blockIdx.x * 256 + threadIdx.x;  // 32768 threads
  int r = t >> 14;
  int n = (t >> 7) & 127, k = t & 127;
  const float* src = w1 + (r ? 3 : 1) * 16384;
  unsigned short* dst = r ? wtI : wtC;
  dst[n * 128 + k] = f2b(src[k * 128 + n]);
}

// ------- fold W2@wout and b2@wout -------

__global__ void prep_k(const float* __restrict__ w2, const float* __restrict__ b2,
                       const float* __restrict__ wout, float* __restrict__ wfC,
                       float* __restrict__ wfI, float* __restrict__ bfC,
                       float* __restrict__ bfI) {
  int t = threadIdx.x;
  int k = t >> 1, o = t & 1;
  float sC = 0.f, sI = 0.f;
  for (int j = 0; j < 128; j++) {
    float wo = wout[j * 2 + o];
    sC += w2[0 * 16384 + k * 128 + j] * wo;
    sI += w2[2 * 16384 + k * 128 + j] * wo;
  }
  wfC[k * 2 + o] = sC;
  wfI[k * 2 + o] = sI;
  if (t < 2) {
    float s = 0.f;
    for (int j = 0; j < 128; j++) s += b2[0 * 128 + j] * wout[j * 2 + t];
    bfC[t] = s;
  } else if (t < 4) {
    int oo = t - 2;
    float s = 0.f;
    for (int j = 0; j < 128; j++) s += b2[2 * 128 + j] * wout[j * 2 + oo];
    bfI[oo] = s;
  }
}

// ------- layer1 source aggregation: bf16 rows, fp32 accumulate, bf16 out -------
// 16 lanes per row (16B = 8 bf16 each), 16 rows per block, 2-edge unroll.

__global__ void aggf_k(const unsigned short* __restrict__ xb,
                       const int* __restrict__ off1, const int* __restrict__ deg1,
                       const int* __restrict__ csr1, unsigned short* __restrict__ accC,
                       const int* __restrict__ off3, const int* __restrict__ deg3,
                       const int* __restrict__ csr3, unsigned short* __restrict__ accI) {
  int gt = blockIdx.x * 256 + threadIdx.x;
  int rid = gt >> 4, lane = gt & 15;
  if (rid >= NCARD + NIP) return;
  const int* off; const int* deg; const int* csr; unsigned short* acc; int row;
  if (rid < NCARD) { off = off1; deg = deg1; csr = csr1; acc = accC; row = rid; }
  else { off = off3; deg = deg3; csr = csr3; acc = accI; row = rid - NCARD; }
  int start = off[row], cnt = deg[row];
  float a[8] = {0.f, 0.f, 0.f, 0.f, 0.f, 0.f, 0.f, 0.f};
  int i = 0;
  for (; i + 2 <= cnt; i += 2) {
    int s0 = csr[start + i], s1 = csr[start + i + 1];
    uint4 v0 = *(const uint4*)(xb + (size_t)s0 * 128 + lane * 8);
    uint4 v1 = *(const uint4*)(xb + (size_t)s1 * 128 + lane * 8);
    unsigned w[8] = {v0.x, v0.y, v0.z, v0.w, v1.x, v1.y, v1.z, v1.w};
#pragma unroll
    for (int j = 0; j < 8; j++) {
      a[(j & 3) * 2] += __uint_as_float(w[j] << 16);
      a[(j & 3) * 2 + 1] += __uint_as_float(w[j] & 0xffff0000u);
    }
  }
  if (i < cnt) {
    int s0 = csr[start + i];
    uint4 v0 = *(const uint4*)(xb + (size_t)s0 * 128 + lane * 8);
    unsigned w[4] = {v0.x, v0.y, v0.z, v0.w};
#pragma unroll
    for (int j = 0; j < 4; j++) {
      a[j * 2] += __uint_as_float(w[j] << 16);
      a[j * 2 + 1] += __uint_as_float(w[j] & 0xffff0000u);
    }
  }
  uint4 o;
  o.x = (unsigned)f2b(a[0]) | ((unsigned)f2b(a[1]) << 16);
  o.y = (unsigned)f2b(a[2]) | ((unsigned)f2b(a[3]) << 16);
  o.z = (unsigned)f2b(a[4]) | ((unsigned)f2b(a[5]) << 16);
  o.w = (unsigned)f2b(a[6]) | ((unsigned)f2b(a[7]) << 16);
  *(uint4*)(acc + (size_t)row * 128 + lane * 8) = o;
}

// ------- layer1 transform via MFMA + leaky + fold-to-z epilogue -------
// Per wave: 32 rows x 128 cols, K=128. A from bf16 acc (global), B from bf16
// transposed W (global, L2-resident). C/D layout: col=lane&15, row=(lane>>4)*4+reg.
// A layout: A[m=lane&15][k=(lane>>4)*8+j].

__global__ __launch_bounds__(256) void gemm_mfma_k(
    const unsigned short* __restrict__ accC, const unsigned short* __restrict__ accI,
    const unsigned short* __restrict__ wtC, const unsigned short* __restrict__ wtI,
    const float* __restrict__ b1, const int* __restrict__ deg1,
    const int* __restrict__ deg3, const float* __restrict__ wfC,
    const float* __restrict__ wfI, const float* __restrict__ bfC,
    const float* __restrict__ bfI, float* __restrict__ zc, float* __restrict__ zi,
    int gbC) {
  int bid = blockIdx.x;
  const unsigned short* accb; const unsigned short* wt; const float* bias;
  const int* deg; const float* wf; const float* bf; float* zout; int M; int lb;
  if (bid < gbC) {
    accb = accC; wt = wtC; bias = b1 + 128; deg = deg1;
    wf = wfC; bf = bfC; zout = zc; M = NCARD; lb = bid;
  } else {
    accb = accI; wt = wtI; bias = b1 + 384; deg = deg3;
    wf = wfI; bf = bfI; zout = zi; M = NIP; lb = bid - gbC;
  }
  int wave = threadIdx.x >> 6, lane = threadIdx.x & 63;
  int q = lane >> 4, cl = lane & 15;
  int r0w = lb * 128 + wave * 32;

  // A fragments: rows r0w + rt*16 + cl, k = ks*32 + q*8 (+j). OOB rows read pad.
  s8v af[2][4];
#pragma unroll
  for (int rt = 0; rt < 2; rt++)
#pragma unroll
    for (int ks = 0; ks < 4; ks++)
      af[rt][ks] = *(const s8v*)(accb + (size_t)(r0w + rt * 16 + cl) * 128 + ks * 32 + q * 8);

  f4v acc[2][8];
#pragma unroll
  for (int rt = 0; rt < 2; rt++)
#pragma unroll
    for (int nt = 0; nt < 8; nt++) acc[rt][nt] = (f4v){0.f, 0.f, 0.f, 0.f};

#pragma unroll
  for (int nt = 0; nt < 8; nt++) {
#pragma unroll
    for (int ks = 0; ks < 4; ks++) {
      s8v bfr = *(const s8v*)(wt + (size_t)(nt * 16 + cl) * 128 + ks * 32 + q * 8);
      acc[0][nt] = __builtin_amdgcn_mfma_f32_16x16x32_bf16(af[0][ks], bfr, acc[0][nt], 0, 0, 0);
      acc[1][nt] = __builtin_amdgcn_mfma_f32_16x16x32_bf16(af[1][ks], bfr, acc[1][nt], 0, 0, 0);
    }
  }

  // epilogue: h = C/deg + b1 -> leaky -> z = h @ wf (+bf), reduce over cols
  float2 wfv[8];
  float b1v[8];
#pragma unroll
  for (int nt = 0; nt < 8; nt++) {
    wfv[nt] = ((const float2*)wf)[nt * 16 + cl];
    b1v[nt] = bias[nt * 16 + cl];
  }
  float2 bf2 = *(const float2*)bf;
#pragma unroll
  for (int rt = 0; rt < 2; rt++) {
#pragma unroll
    for (int reg = 0; reg < 4; reg++) {
      int row = r0w + rt * 16 + q * 4 + reg;
      int d = (row < M) ? deg[row] : 0;
      float sc = (d > 0) ? 1.f / (float)d : 0.f;
      float p0 = 0.f, p1 = 0.f;
#pragma unroll
      for (int nt = 0; nt < 8; nt++) {
        float h = 0.f;
        if (d > 0) {
          h = acc[rt][nt][reg] * sc + b1v[nt];
          h = h > 0.f ? h : 0.01f * h;
        }
        p0 += h * wfv[nt].x;
        p1 += h * wfv[nt].y;
      }
#pragma unroll
      for (int o = 1; o < 16; o <<= 1) {
        p0 += __shfl_xor(p0, o);
        p1 += __shfl_xor(p1, o);
      }
      if (cl == 0 && row < M) {
        ((float2*)zout)[row] = make_float2(p0 + bf2.x, p1 + bf2.y);
      }
    }
  }
}

// ------- target-side: edge-parallel scatter of z (8B per edge) -------

__global__ void scatterf_k(const int* __restrict__ s0, const int* __restrict__ d0,
                           const float* __restrict__ zc, float* __restrict__ tsum0,
                           const int* __restrict__ s2, const int* __restrict__ d2,
                           const float* __restrict__ zi, float* __restrict__ tsum2) {
  int t = blockIdx.x * 256 + threadIdx.x;
  if (t < NE) {
    float2 z = ((const float2*)zc)[s0[t]];
    int d = d0[t];
    atomicAdd(&tsum0[d * 2], z.x);
    atomicAdd(&tsum0[d * 2 + 1], z.y);
  } else if (t < 2 * NE) {
    int e = t - NE;
    float2 z = ((const float2*)zi)[s2[e]];
    int d = d2[e];
    atomicAdd(&tsum2[d * 2], z.x);
    atomicAdd(&tsum2[d * 2 + 1], z.y);
  }
}

// ------- per-target mean over both relations + bout + softmax -------

__global__ void final3_k(const float* __restrict__ tsum0, const int* __restrict__ deg0,
                         const float* __restrict__ tsum2, const int* __restrict__ deg2,
                         const float* __restrict__ bout, float* __restrict__ out) {
  int t = blockIdx.x * 256 + threadIdx.x;
  if (t >= NT) return;
  float l0 = bout[0], l1 = bout[1];
  int d0 = deg0[t];
  if (d0 > 0) {
    float inv = 1.f / (float)d0;
    l0 += tsum0[t * 2] * inv;
    l1 += tsum0[t * 2 + 1] * inv;
  }
  int d2 = deg2[t];
  if (d2 > 0) {
    float inv = 1.f / (float)d2;
    l0 += tsum2[t * 2] * inv;
    l1 += tsum2[t * 2 + 1] * inv;
  }
  float m = fmaxf(l0, l1);
  float e0 = expf(l0 - m), e1 = expf(l1 - m);
  float inv = 1.f / (e0 + e1);
  ((float2*)out)[t] = make_float2(e0 * inv, e1 * inv);
}

// ---------------- launch ----------------

extern "C" void kernel_launch(void* const* d_in, const int* in_sizes, int n_in,
                              void* d_out, int out_size, void* d_ws, size_t ws_size,
                              hipStream_t stream) {
  const float* x_target = (const float*)d_in[0];
  const float* w1 = (const float*)d_in[3];
  const float* b1 = (const float*)d_in[4];
  const float* w2 = (const float*)d_in[5];
  const float* b2 = (const float*)d_in[6];
  const float* wout = (const float*)d_in[7];
  const float* bout = (const float*)d_in[8];
  const int* src0 = (const int*)d_in[9];
  const int* dst0 = (const int*)d_in[10];
  const int* src1 = (const int*)d_in[11];
  const int* dst1 = (const int*)d_in[12];
  const int* src2 = (const int*)d_in[13];
  const int* dst2 = (const int*)d_in[14];
  const int* src3 = (const int*)d_in[15];
  const int* dst3 = (const int*)d_in[16];
  float* out = (float*)d_out;

  char* p = (char*)d_ws;
  auto alloc = [&](size_t bytes) -> char* {
    char* r = p;
    p += (bytes + 255) & ~(size_t)255;
    return r;
  };
  // --- zero region ---
  int* deg1 = (int*)alloc(NCARD * 4);
  int* cur1 = (int*)alloc(NCARD * 4);
  int* deg3 = (int*)alloc(NIP * 4);
  int* cur3 = (int*)alloc(NIP * 4);
  int* deg0 = (int*)alloc(NT * 4);
  int* deg2 = (int*)alloc(NT * 4);
  float* tsum0 = (float*)alloc((size_t)NT * 2 * 4);
  float* tsum2 = (float*)alloc((size_t)NT * 2 * 4);
  size_t zero_bytes = (size_t)(p - (char*)d_ws);
  // --- rest ---
  int* off1 = (int*)alloc(NCARD * 4);
  int* off3 = (int*)alloc(NIP * 4);
  int* bs1 = (int*)alloc(1024 * 4);
  int* bs3 = (int*)alloc(1024 * 4);
  int* csr1 = (int*)alloc(NE * 4);
  int* csr3 = (int*)alloc(NE * 4);
  unsigned short* xb = (unsigned short*)alloc((size_t)NT * 128 * 2);
  unsigned short* accC = (unsigned short*)alloc((size_t)NCARD * 128 * 2);
  unsigned short* accI = (unsigned short*)alloc((size_t)NIP * 128 * 2);
  alloc(128 * 128 * 2);  // pad: OOB-row A-fragment reads from the last block
  unsigned short* wtC = (unsigned short*)alloc(16384 * 2);
  unsigned short* wtI = (unsigned short*)alloc(16384 * 2);
  float* zc = (float*)alloc((size_t)NCARD * 2 * 4);
  float* zi = (float*)alloc((size_t)NIP * 2 * 4);
  float* wfC = (float*)alloc(256 * 4);
  float* wfI = (float*)alloc(256 * 4);
  float* bfC = (float*)alloc(2 * 4);
  float* bfI = (float*)alloc(2 * 4);

  hipMemsetAsync(d_ws, 0, zero_bytes, stream);

  hist4_k<<<(4 * NE + 255) / 256, 256, 0, stream>>>(dst1, dst3, dst0, dst2,
                                                    deg1, deg3, deg0, deg2);
  int nb1 = (NCARD + 255) / 256, nb3 = (NIP + 255) / 256;
  scan1f_k<<<nb1 + nb3, 256, 0, stream>>>(deg1, off1, bs1, nb1, NCARD,
                                          deg3, off3, bs3, NIP);
  scan2f_k<<<2, 1024, 0, stream>>>(bs1, nb1, bs3, nb3);
  scan3f_k<<<nb1 + nb3, 256, 0, stream>>>(off1, bs1, cur1, nb1, NCARD,
                                          off3, bs3, cur3, NIP);
  fillf_k<<<(2 * NE + 255) / 256, 256, 0, stream>>>(src1, dst1, cur1, csr1,
                                                    src3, dst3, cur3, csr3);

  cvt_k<<<(int)(((long)NT * 128 / 4 + 255) / 256), 256, 0, stream>>>(x_target, xb);
  wt_k<<<128, 256, 0, stream>>>(w1, wtC, wtI);
  prep_k<<<1, 256, 0, stream>>>(w2, b2, wout, wfC, wfI, bfC, bfI);

  aggf_k<<<(NCARD + NIP) / 16, 256, 0, stream>>>(xb, off1, deg1, csr1, accC,
                                                 off3, deg3, csr3, accI);

  int gbC = (NCARD + 127) / 128, gbI = (NIP + 127) / 128;
  gemm_mfma_k<<<gbC + gbI, 256, 0, stream>>>(accC, accI, wtC, wtI, b1, deg1, deg3,
                                             wfC, wfI, bfC, bfI, zc, zi, gbC);

  scatterf_k<<<(2 * NE + 255) / 256, 256, 0, stream>>>(src0, dst0, zc, tsum0,
                                                       src2, dst2, zi, tsum2);

  final3_k<<<(NT + 255) / 256, 256, 0, stream>>>(tsum0, deg0, tsum2, deg2, bout, out);
}

// Round 4
// 408.904 us; speedup vs baseline: 1.9752x; 1.1476x over previous
//
#include <hip/hip_runtime.h>

// HeteroRGCN forward, MI355X. Structure (rounds 1-3):
//  - Only h2["target"] matters => layer1 etypes 1,3; layer2 etypes 0,2. x_card/x_ip dead.
//  - Layer1 aggregate-first; layer2+output folded to Wfold=W2@wout (2 cols/node).
//  - bf16 storage + MFMA 16x16x32 for the 128x128 transform; fp32 accumulate.
//  - Round 4: single-atomic CSR build (hist returns per-edge rank => atomic-free fill),
//    target side is CSR-gather (scatterf/final3 deleted), front fused into one launch.

#define NT 200000
#define NCARD 100000
#define NIP 100000
#define NE 300000

typedef __attribute__((ext_vector_type(8))) short s8v;   // 8 bf16 (4 VGPRs)
typedef __attribute__((ext_vector_type(4))) float f4v;   // mfma accumulator

__device__ __forceinline__ unsigned short f2b(float f) {
  unsigned u = __float_as_uint(f);
  u = (u + 0x7fff + ((u >> 16) & 1)) >> 16;  // RNE (finite inputs)
  return (unsigned short)u;
}

// ---------------- fused front: hist+rank (4 rel) | W1 transpose | Wfold prep | cvt ----------------
// Block ranges: [0,4688) hist, [4688,4816) wt, [4816] prep, [4817,29817) cvt.

#define NB_HIST 4688
#define NB_WT 128
#define NB_CVT 25000

__global__ void front_k(const float* __restrict__ x, const float* __restrict__ w1,
                        const float* __restrict__ w2, const float* __restrict__ b2,
                        const float* __restrict__ wout,
                        const int* __restrict__ d1, const int* __restrict__ d3,
                        const int* __restrict__ d0, const int* __restrict__ d2,
                        int* __restrict__ deg1, int* __restrict__ deg3,
                        int* __restrict__ deg0, int* __restrict__ deg2,
                        int* __restrict__ rk1, int* __restrict__ rk3,
                        int* __restrict__ rk0, int* __restrict__ rk2,
                        unsigned short* __restrict__ xb, unsigned short* __restrict__ wtC,
                        unsigned short* __restrict__ wtI, float* __restrict__ wfC,
                        float* __restrict__ wfI, float* __restrict__ bfC,
                        float* __restrict__ bfI) {
  int bid = blockIdx.x, tid = threadIdx.x;
  if (bid < NB_HIST) {
    int t = bid * 256 + tid;
    if (t < NE) rk1[t] = atomicAdd(&deg1[d1[t]], 1);
    else if (t < 2 * NE) { int e = t - NE; rk3[e] = atomicAdd(&deg3[d3[e]], 1); }
    else if (t < 3 * NE) { int e = t - 2 * NE; rk0[e] = atomicAdd(&deg0[d0[e]], 1); }
    else if (t < 4 * NE) { int e = t - 3 * NE; rk2[e] = atomicAdd(&deg2[d2[e]], 1); }
  } else if (bid < NB_HIST + NB_WT) {
    int t = (bid - NB_HIST) * 256 + tid;  // 32768
    int r = t >> 14;
    int n = (t >> 7) & 127, k = t & 127;
    const float* src = w1 + (r ? 3 : 1) * 16384;
    unsigned short* dst = r ? wtI : wtC;
    dst[n * 128 + k] = f2b(src[k * 128 + n]);
  } else if (bid == NB_HIST + NB_WT) {
    int k = tid >> 1, o = tid & 1;
    float sC = 0.f, sI = 0.f;
    for (int j = 0; j < 128; j++) {
      float wo = wout[j * 2 + o];
      sC += w2[0 * 16384 + k * 128 + j] * wo;
      sI += w2[2 * 16384 + k * 128 + j] * wo;
    }
    wfC[k * 2 + o] = sC;
    wfI[k * 2 + o] = sI;
    if (tid < 2) {
      float s = 0.f;
      for (int j = 0; j < 128; j++) s += b2[0 * 128 + j] * wout[j * 2 + tid];
      bfC[tid] = s;
    } else if (tid < 4) {
      int oo = tid - 2;
      float s = 0.f;
      for (int j = 0; j < 128; j++) s += b2[2 * 128 + j] * wout[j * 2 + oo];
      bfI[oo] = s;
    }
  } else {
    long i = (long)(bid - (NB_HIST + NB_WT + 1)) * 256 + tid;  // one float4 each
    const long n4 = (long)NT * 128 / 4;
    if (i < n4) {
      float4 v = ((const float4*)x)[i];
      uint2 o;
      o.x = (unsigned)f2b(v.x) | ((unsigned)f2b(v.y) << 16);
      o.y = (unsigned)f2b(v.z) | ((unsigned)f2b(v.w) << 16);
      ((uint2*)xb)[i] = o;
    }
  }
}

// ---------------- scans over degrees -> start offsets (4 relations fused) ----------------

__global__ void scan1q_k(const int* __restrict__ deg1, int* __restrict__ off1,
                         int* __restrict__ bs1, int nb1,
                         const int* __restrict__ deg3, int* __restrict__ off3,
                         int* __restrict__ bs3, int nb3,
                         const int* __restrict__ deg0, int* __restrict__ off0,
                         int* __restrict__ bs0, int nb0,
                         const int* __restrict__ deg2, int* __restrict__ off2,
                         int* __restrict__ bs2) {
  __shared__ int s[256];
  int bid = blockIdx.x;
  const int* deg; int* off; int* bsum; int N; int lb;
  if (bid < nb1) { deg = deg1; off = off1; bsum = bs1; N = NCARD; lb = bid; }
  else if (bid < nb1 + nb3) { deg = deg3; off = off3; bsum = bs3; N = NIP; lb = bid - nb1; }
  else if (bid < nb1 + nb3 + nb0) { deg = deg0; off = off0; bsum = bs0; N = NT; lb = bid - nb1 - nb3; }
  else { deg = deg2; off = off2; bsum = bs2; N = NT; lb = bid - nb1 - nb3 - nb0; }
  int tid = threadIdx.x;
  int i = lb * 256 + tid;
  int v = (i < N) ? deg[i] : 0;
  s[tid] = v;
  __syncthreads();
  for (int o = 1; o < 256; o <<= 1) {
    int t = (tid >= o) ? s[tid - o] : 0;
    __syncthreads();
    s[tid] += t;
    __syncthreads();
  }
  if (i < N) off[i] = s[tid] - v;
  if (tid == 255) bsum[lb] = s[255];
}

__global__ void scan2q_k(int* __restrict__ bs1, int nb1, int* __restrict__ bs3, int nb3,
                         int* __restrict__ bs0, int nb0, int* __restrict__ bs2, int nb2) {
  __shared__ int s[1024];
  int* bs; int nb;
  if (blockIdx.x == 0) { bs = bs1; nb = nb1; }
  else if (blockIdx.x == 1) { bs = bs3; nb = nb3; }
  else if (blockIdx.x == 2) { bs = bs0; nb = nb0; }
  else { bs = bs2; nb = nb2; }
  int t = threadIdx.x;
  int v = (t < nb) ? bs[t] : 0;
  s[t] = v;
  __syncthreads();
  for (int o = 1; o < 1024; o <<= 1) {
    int u = (t >= o) ? s[t - o] : 0;
    __syncthreads();
    s[t] += u;
    __syncthreads();
  }
  if (t < nb) bs[t] = s[t] - v;
}

__global__ void scan3q_k(int* __restrict__ off1, const int* __restrict__ bs1, int nb1,
                         int* __restrict__ off3, const int* __restrict__ bs3, int nb3,
                         int* __restrict__ off0, const int* __restrict__ bs0, int nb0,
                         int* __restrict__ off2, const int* __restrict__ bs2) {
  int bid = blockIdx.x;
  int* off; const int* bsum; int N; int lb;
  if (bid < nb1) { off = off1; bsum = bs1; N = NCARD; lb = bid; }
  else if (bid < nb1 + nb3) { off = off3; bsum = bs3; N = NIP; lb = bid - nb1; }
  else if (bid < nb1 + nb3 + nb0) { off = off0; bsum = bs0; N = NT; lb = bid - nb1 - nb3; }
  else { off = off2; bsum = bs2; N = NT; lb = bid - nb1 - nb3 - nb0; }
  int i = lb * 256 + threadIdx.x;
  if (i < N) off[i] += bsum[lb];
}

// ---------------- atomic-free CSR fill (rank trick), 4 relations ----------------

__global__ void fill4_k(const int* __restrict__ s1, const int* __restrict__ d1,
                        const int* __restrict__ rk1, const int* __restrict__ off1,
                        int* __restrict__ csr1,
                        const int* __restrict__ s3, const int* __restrict__ d3,
                        const int* __restrict__ rk3, const int* __restrict__ off3,
                        int* __restrict__ csr3,
                        const int* __restrict__ s0, const int* __restrict__ d0,
                        const int* __restrict__ rk0, const int* __restrict__ off0,
                        int* __restrict__ csr0,
                        const int* __restrict__ s2, const int* __restrict__ d2,
                        const int* __restrict__ rk2, const int* __restrict__ off2,
                        int* __restrict__ csr2) {
  int t = blockIdx.x * 256 + threadIdx.x;
  if (t < NE) csr1[off1[d1[t]] + rk1[t]] = s1[t];
  else if (t < 2 * NE) { int e = t - NE; csr3[off3[d3[e]] + rk3[e]] = s3[e]; }
  else if (t < 3 * NE) { int e = t - 2 * NE; csr0[off0[d0[e]] + rk0[e]] = s0[e]; }
  else if (t < 4 * NE) { int e = t - 3 * NE; csr2[off2[d2[e]] + rk2[e]] = s2[e]; }
}

// ------- layer1 source aggregation: one wave per dst row -------
// 4 edge-groups x 16 feature-lanes (16B each); shfl_xor reduce across groups.

__global__ void aggf_k(const unsigned short* __restrict__ xb,
                       const int* __restrict__ off1, const int* __restrict__ deg1,
                       const int* __restrict__ csr1, unsigned short* __restrict__ accC,
                       const int* __restrict__ off3, const int* __restrict__ deg3,
                       const int* __restrict__ csr3, unsigned short* __restrict__ accI) {
  int w = (blockIdx.x * 256 + threadIdx.x) >> 6;
  int lane = threadIdx.x & 63;
  if (w >= NCARD + NIP) return;
  const int* off; const int* deg; const int* csr; unsigned short* acc; int row;
  if (w < NCARD) { off = off1; deg = deg1; csr = csr1; acc = accC; row = w; }
  else { off = off3; deg = deg3; csr = csr3; acc = accI; row = w - NCARD; }
  int start = off[row], cnt = deg[row];
  int eg = lane >> 4, fl = lane & 15;
  float a[8] = {0.f, 0.f, 0.f, 0.f, 0.f, 0.f, 0.f, 0.f};
  for (int i = eg; i < cnt; i += 4) {
    int s = csr[start + i];
    uint4 v = *(const uint4*)(xb + (size_t)s * 128 + fl * 8);
    a[0] += __uint_as_float(v.x << 16);
    a[1] += __uint_as_float(v.x & 0xffff0000u);
    a[2] += __uint_as_float(v.y << 16);
    a[3] += __uint_as_float(v.y & 0xffff0000u);
    a[4] += __uint_as_float(v.z << 16);
    a[5] += __uint_as_float(v.z & 0xffff0000u);
    a[6] += __uint_as_float(v.w << 16);
    a[7] += __uint_as_float(v.w & 0xffff0000u);
  }
#pragma unroll
  for (int j = 0; j < 8; j++) {
    a[j] += __shfl_xor(a[j], 16);
    a[j] += __shfl_xor(a[j], 32);
  }
  if (eg == 0) {
    uint4 o;
    o.x = (unsigned)f2b(a[0]) | ((unsigned)f2b(a[1]) << 16);
    o.y = (unsigned)f2b(a[2]) | ((unsigned)f2b(a[3]) << 16);
    o.z = (unsigned)f2b(a[4]) | ((unsigned)f2b(a[5]) << 16);
    o.w = (unsigned)f2b(a[6]) | ((unsigned)f2b(a[7]) << 16);
    *(uint4*)(acc + (size_t)row * 128 + fl * 8) = o;
  }
}

// ------- layer1 transform via MFMA + leaky + fold-to-z epilogue -------
// Per wave: 32 rows x 128 cols, K=128. C/D layout: col=lane&15, row=(lane>>4)*4+reg.
// A layout: A[m=lane&15][k=(lane>>4)*8+j].

__global__ __launch_bounds__(256) void gemm_mfma_k(
    const unsigned short* __restrict__ accC, const unsigned short* __restrict__ accI,
    const unsigned short* __restrict__ wtC, const unsigned short* __restrict__ wtI,
    const float* __restrict__ b1, const int* __restrict__ deg1,
    const int* __restrict__ deg3, const float* __restrict__ wfC,
    const float* __restrict__ wfI, const float* __restrict__ bfC,
    const float* __restrict__ bfI, float* __restrict__ zc, float* __restrict__ zi,
    int gbC) {
  int bid = blockIdx.x;
  const unsigned short* accb; const unsigned short* wt; const float* bias;
  const int* deg; const float* wf; const float* bf; float* zout; int M; int lb;
  if (bid < gbC) {
    accb = accC; wt = wtC; bias = b1 + 128; deg = deg1;
    wf = wfC; bf = bfC; zout = zc; M = NCARD; lb = bid;
  } else {
    accb = accI; wt = wtI; bias = b1 + 384; deg = deg3;
    wf = wfI; bf = bfI; zout = zi; M = NIP; lb = bid - gbC;
  }
  int wave = threadIdx.x >> 6, lane = threadIdx.x & 63;
  int q = lane >> 4, cl = lane & 15;
  int r0w = lb * 128 + wave * 32;

  s8v af[2][4];
#pragma unroll
  for (int rt = 0; rt < 2; rt++)
#pragma unroll
    for (int ks = 0; ks < 4; ks++)
      af[rt][ks] = *(const s8v*)(accb + (size_t)(r0w + rt * 16 + cl) * 128 + ks * 32 + q * 8);

  f4v acc[2][8];
#pragma unroll
  for (int rt = 0; rt < 2; rt++)
#pragma unroll
    for (int nt = 0; nt < 8; nt++) acc[rt][nt] = (f4v){0.f, 0.f, 0.f, 0.f};

#pragma unroll
  for (int nt = 0; nt < 8; nt++) {
#pragma unroll
    for (int ks = 0; ks < 4; ks++) {
      s8v bfr = *(const s8v*)(wt + (size_t)(nt * 16 + cl) * 128 + ks * 32 + q * 8);
      acc[0][nt] = __builtin_amdgcn_mfma_f32_16x16x32_bf16(af[0][ks], bfr, acc[0][nt], 0, 0, 0);
      acc[1][nt] = __builtin_amdgcn_mfma_f32_16x16x32_bf16(af[1][ks], bfr, acc[1][nt], 0, 0, 0);
    }
  }

  float2 wfv[8];
  float b1v[8];
#pragma unroll
  for (int nt = 0; nt < 8; nt++) {
    wfv[nt] = ((const float2*)wf)[nt * 16 + cl];
    b1v[nt] = bias[nt * 16 + cl];
  }
  float2 bf2 = *(const float2*)bf;
#pragma unroll
  for (int rt = 0; rt < 2; rt++) {
#pragma unroll
    for (int reg = 0; reg < 4; reg++) {
      int row = r0w + rt * 16 + q * 4 + reg;
      int d = (row < M) ? deg[row] : 0;
      float sc = (d > 0) ? 1.f / (float)d : 0.f;
      float p0 = 0.f, p1 = 0.f;
#pragma unroll
      for (int nt = 0; nt < 8; nt++) {
        float h = 0.f;
        if (d > 0) {
          h = acc[rt][nt][reg] * sc + b1v[nt];
          h = h > 0.f ? h : 0.01f * h;
        }
        p0 += h * wfv[nt].x;
        p1 += h * wfv[nt].y;
      }
#pragma unroll
      for (int o = 1; o < 16; o <<= 1) {
        p0 += __shfl_xor(p0, o);
        p1 += __shfl_xor(p1, o);
      }
      if (cl == 0 && row < M) {
        ((float2*)zout)[row] = make_float2(p0 + bf2.x, p1 + bf2.y);
      }
    }
  }
}

// ------- target-side: CSR gather of z + mean + softmax (no atomics) -------

__global__ void finalg_k(const float* __restrict__ zc, const float* __restrict__ zi,
                         const int* __restrict__ off0, const int* __restrict__ deg0,
                         const int* __restrict__ csr0, const int* __restrict__ off2,
                         const int* __restrict__ deg2, const int* __restrict__ csr2,
                         const float* __restrict__ bout, float* __restrict__ out) {
  int t = blockIdx.x * 256 + threadIdx.x;
  if (t >= NT) return;
  float l0 = bout[0], l1 = bout[1];
  {
    int d = deg0[t], st = off0[t];
    if (d > 0) {
      float ax = 0.f, ay = 0.f;
      for (int i = 0; i < d; i++) {
        float2 z = ((const float2*)zc)[csr0[st + i]];
        ax += z.x; ay += z.y;
      }
      float inv = 1.f / (float)d;
      l0 += ax * inv; l1 += ay * inv;
    }
  }
  {
    int d = deg2[t], st = off2[t];
    if (d > 0) {
      float ax = 0.f, ay = 0.f;
      for (int i = 0; i < d; i++) {
        float2 z = ((const float2*)zi)[csr2[st + i]];
        ax += z.x; ay += z.y;
      }
      float inv = 1.f / (float)d;
      l0 += ax * inv; l1 += ay * inv;
    }
  }
  float m = fmaxf(l0, l1);
  float e0 = expf(l0 - m), e1 = expf(l1 - m);
  float inv = 1.f / (e0 + e1);
  ((float2*)out)[t] = make_float2(e0 * inv, e1 * inv);
}

// ---------------- launch ----------------

extern "C" void kernel_launch(void* const* d_in, const int* in_sizes, int n_in,
                              void* d_out, int out_size, void* d_ws, size_t ws_size,
                              hipStream_t stream) {
  const float* x_target = (const float*)d_in[0];
  const float* w1 = (const float*)d_in[3];
  const float* b1 = (const float*)d_in[4];
  const float* w2 = (const float*)d_in[5];
  const float* b2 = (const float*)d_in[6];
  const float* wout = (const float*)d_in[7];
  const float* bout = (const float*)d_in[8];
  const int* src0 = (const int*)d_in[9];
  const int* dst0 = (const int*)d_in[10];
  const int* src1 = (const int*)d_in[11];
  const int* dst1 = (const int*)d_in[12];
  const int* src2 = (const int*)d_in[13];
  const int* dst2 = (const int*)d_in[14];
  const int* src3 = (const int*)d_in[15];
  const int* dst3 = (const int*)d_in[16];
  float* out = (float*)d_out;

  char* p = (char*)d_ws;
  auto alloc = [&](size_t bytes) -> char* {
    char* r = p;
    p += (bytes + 255) & ~(size_t)255;
    return r;
  };
  // --- zero region (degree histograms) ---
  int* deg1 = (int*)alloc(NCARD * 4);
  int* deg3 = (int*)alloc(NIP * 4);
  int* deg0 = (int*)alloc(NT * 4);
  int* deg2 = (int*)alloc(NT * 4);
  size_t zero_bytes = (size_t)(p - (char*)d_ws);
  // --- rest ---
  int* rk1 = (int*)alloc(NE * 4);
  int* rk3 = (int*)alloc(NE * 4);
  int* rk0 = (int*)alloc(NE * 4);
  int* rk2 = (int*)alloc(NE * 4);
  int* off1 = (int*)alloc(NCARD * 4);
  int* off3 = (int*)alloc(NIP * 4);
  int* off0 = (int*)alloc(NT * 4);
  int* off2 = (int*)alloc(NT * 4);
  int* bs1 = (int*)alloc(1024 * 4);
  int* bs3 = (int*)alloc(1024 * 4);
  int* bs0 = (int*)alloc(1024 * 4);
  int* bs2 = (int*)alloc(1024 * 4);
  int* csr1 = (int*)alloc(NE * 4);
  int* csr3 = (int*)alloc(NE * 4);
  int* csr0 = (int*)alloc(NE * 4);
  int* csr2 = (int*)alloc(NE * 4);
  unsigned short* xb = (unsigned short*)alloc((size_t)NT * 128 * 2);
  unsigned short* accC = (unsigned short*)alloc((size_t)NCARD * 128 * 2);
  unsigned short* accI = (unsigned short*)alloc((size_t)NIP * 128 * 2);
  alloc(128 * 128 * 2);  // pad: OOB-row A-fragment reads from the last gemm block
  unsigned short* wtC = (unsigned short*)alloc(16384 * 2);
  unsigned short* wtI = (unsigned short*)alloc(16384 * 2);
  float* zc = (float*)alloc((size_t)NCARD * 2 * 4);
  float* zi = (float*)alloc((size_t)NIP * 2 * 4);
  float* wfC = (float*)alloc(256 * 4);
  float* wfI = (float*)alloc(256 * 4);
  float* bfC = (float*)alloc(2 * 4);
  float* bfI = (float*)alloc(2 * 4);

  hipMemsetAsync(d_ws, 0, zero_bytes, stream);

  front_k<<<NB_HIST + NB_WT + 1 + NB_CVT, 256, 0, stream>>>(
      x_target, w1, w2, b2, wout, dst1, dst3, dst0, dst2, deg1, deg3, deg0, deg2,
      rk1, rk3, rk0, rk2, xb, wtC, wtI, wfC, wfI, bfC, bfI);

  int nb1 = (NCARD + 255) / 256, nb3 = (NIP + 255) / 256;
  int nb0 = (NT + 255) / 256, nb2 = (NT + 255) / 256;
  scan1q_k<<<nb1 + nb3 + nb0 + nb2, 256, 0, stream>>>(
      deg1, off1, bs1, nb1, deg3, off3, bs3, nb3, deg0, off0, bs0, nb0, deg2, off2, bs2);
  scan2q_k<<<4, 1024, 0, stream>>>(bs1, nb1, bs3, nb3, bs0, nb0, bs2, nb2);
  scan3q_k<<<nb1 + nb3 + nb0 + nb2, 256, 0, stream>>>(
      off1, bs1, nb1, off3, bs3, nb3, off0, bs0, nb0, off2, bs2);

  fill4_k<<<(4 * NE + 255) / 256, 256, 0, stream>>>(
      src1, dst1, rk1, off1, csr1, src3, dst3, rk3, off3, csr3,
      src0, dst0, rk0, off0, csr0, src2, dst2, rk2, off2, csr2);

  aggf_k<<<(NCARD + NIP + 3) / 4, 256, 0, stream>>>(xb, off1, deg1, csr1, accC,
                                                    off3, deg3, csr3, accI);

  int gbC = (NCARD + 127) / 128, gbI = (NIP + 127) / 128;
  gemm_mfma_k<<<gbC + gbI, 256, 0, stream>>>(accC, accI, wtC, wtI, b1, deg1, deg3,
                                             wfC, wfI, bfC, bfI, zc, zi, gbC);

  finalg_k<<<(NT + 255) / 256, 256, 0, stream>>>(zc, zi, off0, deg0, csr0,
                                                 off2, deg2, csr2, bout, out);
}